// Round 3
// baseline (2184.600 us; speedup 1.0000x reference)
//
#include <hip/hip_runtime.h>
#include <hip/hip_bf16.h>
#include <limits.h>

#define NUM_NODES 100000
#define OUT_CH 64
#define NUM_EDGES 3200000
#define NBINS 500
#define BINSZ 200  // NBINS * BINSZ == NUM_NODES exactly

// ---------- K1: min of edge_index[0] ----------
__global__ void LINK_62689342652831_min_kernel(const int* __restrict__ rows, int n,
                                               int* __restrict__ minp) {
    int tid = blockIdx.x * blockDim.x + threadIdx.x;
    int stride = gridDim.x * blockDim.x;
    int m = INT_MAX;
    for (int i = tid; i < n; i += stride) m = min(m, rows[i]);
    for (int off = 32; off > 0; off >>= 1) m = min(m, __shfl_xor(m, off, 64));
    if ((threadIdx.x & 63) == 0) atomicMin(minp, m);
}

// ---------- K2: transpose W [64][N] -> Wt [N][64] ----------
__global__ void LINK_62689342652831_transpose_kernel(const float* __restrict__ W,
                                                     float* __restrict__ Wt) {
    __shared__ float tile[64][65];
    int n0 = blockIdx.x * 64;
    int tx = threadIdx.x & 63;
    int ty = threadIdx.x >> 6;  // 0..3
    for (int c = ty; c < 64; c += 4) {
        int n = n0 + tx;
        tile[c][tx] = (n < NUM_NODES) ? W[(size_t)c * NUM_NODES + n] : 0.0f;
    }
    __syncthreads();
    for (int i = ty; i < 64; i += 4) {
        int n = n0 + i;
        if (n < NUM_NODES) Wt[(size_t)n * 64 + tx] = tile[tx][i];
    }
}

// ---------- K3: histogram of rows into NBINS bins (LDS-aggregated) ----------
__global__ void LINK_62689342652831_hist_kernel(const int* __restrict__ rows,
                                                const int* __restrict__ minp,
                                                int* __restrict__ bin_count) {
    __shared__ int h[NBINS];
    for (int i = threadIdx.x; i < NBINS; i += blockDim.x) h[i] = 0;
    __syncthreads();
    int minv = *minp;
    int tid = blockIdx.x * blockDim.x + threadIdx.x;
    int stride = gridDim.x * blockDim.x;
    for (int e = tid; e < NUM_EDGES; e += stride) {
        int r = rows[e] - minv;
        atomicAdd(&h[r / BINSZ], 1);
    }
    __syncthreads();
    for (int i = threadIdx.x; i < NBINS; i += blockDim.x)
        if (h[i]) atomicAdd(&bin_count[i], h[i]);
}

// ---------- K4: exclusive scan of bin counts (single block) ----------
__global__ void LINK_62689342652831_scan_kernel(const int* __restrict__ bin_count,
                                                int* __restrict__ bin_start,
                                                int* __restrict__ bin_cursor) {
    __shared__ int sdata[512];
    int t = threadIdx.x;
    int c = (t < NBINS) ? bin_count[t] : 0;
    sdata[t] = c;
    __syncthreads();
    for (int off = 1; off < 512; off <<= 1) {
        int v = 0;
        if (t >= off) v = sdata[t - off];
        __syncthreads();
        if (t >= off) sdata[t] += v;
        __syncthreads();
    }
    int incl = sdata[t];
    if (t == 0) bin_start[0] = 0;
    if (t < NBINS) {
        bin_start[t + 1] = incl;
        bin_cursor[t] = incl - c;  // exclusive
    }
}

// ---------- K5: scatter edges into bins as packed (col | local_row<<17) ----------
__global__ void LINK_62689342652831_binscatter_kernel(const int* __restrict__ rows,
                                                      const int* __restrict__ cols,
                                                      const int* __restrict__ minp,
                                                      int* __restrict__ bin_cursor,
                                                      unsigned int* __restrict__ packed) {
    int minv = *minp;
    int tid = blockIdx.x * blockDim.x + threadIdx.x;
    int stride = gridDim.x * blockDim.x;
    for (int e = tid; e < NUM_EDGES; e += stride) {
        int r = rows[e] - minv;
        int b = r / BINSZ;
        int pos = atomicAdd(&bin_cursor[b], 1);
        packed[pos] = (unsigned int)cols[e] | ((unsigned int)(r - b * BINSZ) << 17);
    }
}

// ---------- K6: per-bin SpMM in LDS + fused bias/log_softmax ----------
__global__ __launch_bounds__(512) void LINK_62689342652831_spmm_kernel(
    const unsigned int* __restrict__ packed, const int* __restrict__ bin_start,
    const float* __restrict__ Wt, const float* __restrict__ bias,
    float* __restrict__ out) {
    __shared__ float acc[BINSZ * OUT_CH];  // 51.2 KB
    int lane = threadIdx.x & 63;
    int wid = threadIdx.x >> 6;  // 0..7
    for (int i = threadIdx.x; i < BINSZ * OUT_CH; i += 512) acc[i] = 0.0f;
    __syncthreads();

    int b = blockIdx.x;
    int s = bin_start[b], e = bin_start[b + 1];

    int i = s + wid;
    // 4x manual unroll for memory-level parallelism on the Wt gather
    for (; i + 24 < e; i += 32) {
        unsigned int p0 = packed[i];
        unsigned int p1 = packed[i + 8];
        unsigned int p2 = packed[i + 16];
        unsigned int p3 = packed[i + 24];
        float v0 = Wt[(size_t)(p0 & 0x1FFFF) * OUT_CH + lane];
        float v1 = Wt[(size_t)(p1 & 0x1FFFF) * OUT_CH + lane];
        float v2 = Wt[(size_t)(p2 & 0x1FFFF) * OUT_CH + lane];
        float v3 = Wt[(size_t)(p3 & 0x1FFFF) * OUT_CH + lane];
        atomicAdd(&acc[(p0 >> 17) * OUT_CH + lane], v0);
        atomicAdd(&acc[(p1 >> 17) * OUT_CH + lane], v1);
        atomicAdd(&acc[(p2 >> 17) * OUT_CH + lane], v2);
        atomicAdd(&acc[(p3 >> 17) * OUT_CH + lane], v3);
    }
    for (; i < e; i += 8) {
        unsigned int p = packed[i];
        float v = Wt[(size_t)(p & 0x1FFFF) * OUT_CH + lane];
        atomicAdd(&acc[(p >> 17) * OUT_CH + lane], v);
    }
    __syncthreads();

    // fused bias + log_softmax epilogue, wave per row
    float bsv = bias[lane];
    int base = b * BINSZ;
    for (int r = wid; r < BINSZ; r += 8) {
        float x = acc[r * OUT_CH + lane] + bsv;
        float m = x;
        for (int off = 32; off > 0; off >>= 1) m = fmaxf(m, __shfl_xor(m, off, 64));
        float ex = expf(x - m);
        float ssum = ex;
        for (int off = 32; off > 0; off >>= 1) ssum += __shfl_xor(ssum, off, 64);
        out[(size_t)(base + r) * OUT_CH + lane] = x - m - logf(ssum);
    }
}

// ---------- fallback (round-1 path) ----------
template <int USE_WT>
__global__ void LINK_62689342652831_scatter_kernel(const int* __restrict__ rows,
                                                   const int* __restrict__ cols,
                                                   const float* __restrict__ Wsrc,
                                                   const int* __restrict__ minp,
                                                   float* __restrict__ out) {
    int lane = threadIdx.x & 63;
    int gw = (blockIdx.x * blockDim.x + threadIdx.x) >> 6;
    int nw = (gridDim.x * blockDim.x) >> 6;
    int minv = *minp;
    for (int e = gw; e < NUM_EDGES; e += nw) {
        int r = rows[e] - minv;
        int c = cols[e];
        float v = USE_WT ? Wsrc[(size_t)c * 64 + lane]
                         : Wsrc[(size_t)lane * NUM_NODES + c];
        unsafeAtomicAdd(&out[(size_t)r * 64 + lane], v);
    }
}

__global__ void LINK_62689342652831_logsoftmax_kernel(float* __restrict__ out,
                                                      const float* __restrict__ bias) {
    int lane = threadIdx.x & 63;
    int gw = (blockIdx.x * blockDim.x + threadIdx.x) >> 6;
    int nw = (gridDim.x * blockDim.x) >> 6;
    float b = bias[lane];
    for (int r = gw; r < NUM_NODES; r += nw) {
        float x = out[(size_t)r * 64 + lane] + b;
        float m = x;
        for (int off = 32; off > 0; off >>= 1) m = fmaxf(m, __shfl_xor(m, off, 64));
        float e = expf(x - m);
        float s = e;
        for (int off = 32; off > 0; off >>= 1) s += __shfl_xor(s, off, 64);
        out[(size_t)r * 64 + lane] = x - m - logf(s);
    }
}

extern "C" void kernel_launch(void* const* d_in, const int* in_sizes, int n_in,
                              void* d_out, int out_size, void* d_ws, size_t ws_size,
                              hipStream_t stream) {
    const int* edges = (const int*)d_in[0];
    const int* rows = edges;
    const int* cols = edges + NUM_EDGES;
    const float* W = (const float*)d_in[1];
    const float* bias = (const float*)d_in[2];
    float* out = (float*)d_out;

    // workspace layout
    char* ws = (char*)d_ws;
    int* minp = (int*)ws;                               // 4 B
    int* bin_count = (int*)(ws + 256);                  // 2000 B
    int* bin_start = (int*)(ws + 4096);                 // 2004 B
    int* bin_cursor = (int*)(ws + 8192);                // 2000 B
    unsigned int* packed = (unsigned int*)(ws + 16384); // 12.8 MB
    size_t packed_bytes = (size_t)NUM_EDGES * 4;
    float* Wt = (float*)(ws + 16384 + packed_bytes);    // 25.6 MB
    size_t wt_bytes = (size_t)NUM_NODES * OUT_CH * sizeof(float);
    size_t need = 16384 + packed_bytes + wt_bytes;

    hipMemsetAsync(minp, 0x7f, sizeof(int), stream);
    LINK_62689342652831_min_kernel<<<2048, 256, 0, stream>>>(rows, NUM_EDGES, minp);

    if (ws_size >= need) {
        hipMemsetAsync(bin_count, 0, NBINS * sizeof(int), stream);
        LINK_62689342652831_transpose_kernel<<<(NUM_NODES + 63) / 64, 256, 0, stream>>>(W, Wt);
        LINK_62689342652831_hist_kernel<<<512, 256, 0, stream>>>(rows, minp, bin_count);
        LINK_62689342652831_scan_kernel<<<1, 512, 0, stream>>>(bin_count, bin_start, bin_cursor);
        LINK_62689342652831_binscatter_kernel<<<2048, 256, 0, stream>>>(rows, cols, minp,
                                                                        bin_cursor, packed);
        LINK_62689342652831_spmm_kernel<<<NBINS, 512, 0, stream>>>(packed, bin_start, Wt,
                                                                   bias, out);
    } else if (ws_size >= 256 + wt_bytes) {
        float* Wt2 = (float*)(ws + 256);
        hipMemsetAsync(d_out, 0, (size_t)out_size * sizeof(float), stream);
        LINK_62689342652831_transpose_kernel<<<(NUM_NODES + 63) / 64, 256, 0, stream>>>(W, Wt2);
        LINK_62689342652831_scatter_kernel<1><<<2048, 256, 0, stream>>>(rows, cols, Wt2, minp, out);
        LINK_62689342652831_logsoftmax_kernel<<<4096, 256, 0, stream>>>(out, bias);
    } else {
        hipMemsetAsync(d_out, 0, (size_t)out_size * sizeof(float), stream);
        LINK_62689342652831_scatter_kernel<0><<<2048, 256, 0, stream>>>(rows, cols, W, minp, out);
        LINK_62689342652831_logsoftmax_kernel<<<4096, 256, 0, stream>>>(out, bias);
    }
}

// Round 4
// 537.600 us; speedup vs baseline: 4.0636x; 4.0636x over previous
//
#include <hip/hip_runtime.h>
#include <hip/hip_bf16.h>
#include <limits.h>

#define NUM_NODES 100000
#define OUT_CH 64
#define NUM_EDGES 3200000
#define SCAN_BLK 1024
#define NSCAN_BLKS ((NUM_NODES + SCAN_BLK - 1) / SCAN_BLK)  // 98

// ---------- K1: fused min-reduce + node-level histogram (raw row ids) ----------
__global__ void LINK_62689342652831_minhist_kernel(const int* __restrict__ rows,
                                                   int* __restrict__ minp,
                                                   int* __restrict__ hist) {
    int tid = blockIdx.x * blockDim.x + threadIdx.x;
    int stride = gridDim.x * blockDim.x;
    int m = INT_MAX;
    for (int e = tid; e < NUM_EDGES; e += stride) {
        int r = rows[e];
        m = min(m, r);
        atomicAdd(&hist[r], 1);
    }
    for (int off = 32; off > 0; off >>= 1) m = min(m, __shfl_xor(m, off, 64));
    if ((threadIdx.x & 63) == 0) atomicMin(minp, m);
}

// ---------- K2: transpose W [64][N] -> Wtb [N][64] bf16 ----------
__global__ void LINK_62689342652831_transpose_kernel(const float* __restrict__ W,
                                                     __hip_bfloat16* __restrict__ Wtb) {
    __shared__ float tile[64][65];
    int n0 = blockIdx.x * 64;
    int tx = threadIdx.x & 63;
    int ty = threadIdx.x >> 6;  // 0..3
    for (int c = ty; c < 64; c += 4) {
        int n = n0 + tx;
        tile[c][tx] = (n < NUM_NODES) ? W[(size_t)c * NUM_NODES + n] : 0.0f;
    }
    __syncthreads();
    for (int i = ty; i < 64; i += 4) {
        int n = n0 + i;
        if (n < NUM_NODES) Wtb[(size_t)n * OUT_CH + tx] = __float2bfloat16(tile[tx][i]);
    }
}

// ---------- K3a: per-block scan (1024 elems/block, 4/thread) ----------
__global__ __launch_bounds__(256) void LINK_62689342652831_scanA_kernel(
    const int* __restrict__ hist, const int* __restrict__ minp,
    int* __restrict__ chunk_incl, int* __restrict__ block_sums) {
    __shared__ int ss[256];
    int minv = *minp;
    int t = threadIdx.x;
    int idx0 = blockIdx.x * SCAN_BLK + t * 4;
    int v[4];
#pragma unroll
    for (int k = 0; k < 4; ++k) {
        int idx = idx0 + k;
        int raw = idx + minv;
        v[k] = (idx < NUM_NODES && raw >= 0 && raw < NUM_NODES) ? hist[raw] : 0;
    }
    // prefix within thread
    int p0 = v[0], p1 = p0 + v[1], p2 = p1 + v[2], p3 = p2 + v[3];
    ss[t] = p3;
    __syncthreads();
    for (int off = 1; off < 256; off <<= 1) {
        int x = (t >= off) ? ss[t - off] : 0;
        __syncthreads();
        ss[t] += x;
        __syncthreads();
    }
    int texcl = ss[t] - p3;
#pragma unroll
    for (int k = 0; k < 4; ++k) {
        int idx = idx0 + k;
        int incl = texcl + (k == 0 ? p0 : k == 1 ? p1 : k == 2 ? p2 : p3);
        if (idx < NUM_NODES) chunk_incl[idx] = incl;
    }
    if (t == 255) block_sums[blockIdx.x] = ss[255];
}

// ---------- K3b: scan of block sums (single block) ----------
__global__ void LINK_62689342652831_scanB_kernel(const int* __restrict__ block_sums,
                                                 int* __restrict__ block_off) {
    __shared__ int ss[128];
    int t = threadIdx.x;
    int v = (t < NSCAN_BLKS) ? block_sums[t] : 0;
    ss[t] = v;
    __syncthreads();
    for (int off = 1; off < 128; off <<= 1) {
        int x = (t >= off) ? ss[t - off] : 0;
        __syncthreads();
        ss[t] += x;
        __syncthreads();
    }
    if (t < NSCAN_BLKS) block_off[t] = ss[t] - v;  // exclusive
}

// ---------- K3c: produce row_start (exclusive) + cursor copy ----------
__global__ void LINK_62689342652831_scanC_kernel(
    const int* __restrict__ chunk_incl, const int* __restrict__ hist,
    const int* __restrict__ minp, const int* __restrict__ block_off,
    int* __restrict__ row_start, int* __restrict__ cursor) {
    int i = blockIdx.x * blockDim.x + threadIdx.x;
    if (i >= NUM_NODES) return;
    int minv = *minp;
    int raw = i + minv;
    int c = (raw >= 0 && raw < NUM_NODES) ? hist[raw] : 0;
    int g = chunk_incl[i] + block_off[i / SCAN_BLK];
    int excl = g - c;
    row_start[i] = excl;
    cursor[i] = excl;
    if (i == NUM_NODES - 1) row_start[NUM_NODES] = g;
}

// ---------- K4: scatter cols into CSR order ----------
__global__ void LINK_62689342652831_csrscatter_kernel(const int* __restrict__ rows,
                                                      const int* __restrict__ cols,
                                                      const int* __restrict__ minp,
                                                      int* __restrict__ cursor,
                                                      int* __restrict__ csr_col) {
    int minv = *minp;
    int tid = blockIdx.x * blockDim.x + threadIdx.x;
    int stride = gridDim.x * blockDim.x;
    for (int e = tid; e < NUM_EDGES; e += stride) {
        int r = rows[e] - minv;
        int pos = atomicAdd(&cursor[r], 1);
        csr_col[pos] = cols[e];
    }
}

// ---------- K5: wave-per-row CSR SpMM + fused bias/log_softmax ----------
__global__ __launch_bounds__(256) void LINK_62689342652831_spmmcsr_kernel(
    const int* __restrict__ row_start, const int* __restrict__ csr_col,
    const __hip_bfloat16* __restrict__ Wtb, const float* __restrict__ bias,
    float* __restrict__ out) {
    int lane = threadIdx.x & 63;
    int r = (blockIdx.x * blockDim.x + threadIdx.x) >> 6;
    if (r >= NUM_NODES) return;
    int s = row_start[r], e = row_start[r + 1];
    float acc = 0.0f;
    int i = s;
    for (; i + 8 <= e; i += 8) {
        int c0 = csr_col[i];
        int c1 = csr_col[i + 1];
        int c2 = csr_col[i + 2];
        int c3 = csr_col[i + 3];
        int c4 = csr_col[i + 4];
        int c5 = csr_col[i + 5];
        int c6 = csr_col[i + 6];
        int c7 = csr_col[i + 7];
        float v0 = __bfloat162float(Wtb[(size_t)c0 * OUT_CH + lane]);
        float v1 = __bfloat162float(Wtb[(size_t)c1 * OUT_CH + lane]);
        float v2 = __bfloat162float(Wtb[(size_t)c2 * OUT_CH + lane]);
        float v3 = __bfloat162float(Wtb[(size_t)c3 * OUT_CH + lane]);
        float v4 = __bfloat162float(Wtb[(size_t)c4 * OUT_CH + lane]);
        float v5 = __bfloat162float(Wtb[(size_t)c5 * OUT_CH + lane]);
        float v6 = __bfloat162float(Wtb[(size_t)c6 * OUT_CH + lane]);
        float v7 = __bfloat162float(Wtb[(size_t)c7 * OUT_CH + lane]);
        acc += ((v0 + v1) + (v2 + v3)) + ((v4 + v5) + (v6 + v7));
    }
    for (; i < e; ++i)
        acc += __bfloat162float(Wtb[(size_t)csr_col[i] * OUT_CH + lane]);

    float x = acc + bias[lane];
    float m = x;
    for (int off = 32; off > 0; off >>= 1) m = fmaxf(m, __shfl_xor(m, off, 64));
    float ex = expf(x - m);
    float ssum = ex;
    for (int off = 32; off > 0; off >>= 1) ssum += __shfl_xor(ssum, off, 64);
    out[(size_t)r * OUT_CH + lane] = x - m - logf(ssum);
}

// ---------- fallback (round-1 path, direct W) ----------
__global__ void LINK_62689342652831_min_kernel(const int* __restrict__ rows, int n,
                                               int* __restrict__ minp) {
    int tid = blockIdx.x * blockDim.x + threadIdx.x;
    int stride = gridDim.x * blockDim.x;
    int m = INT_MAX;
    for (int i = tid; i < n; i += stride) m = min(m, rows[i]);
    for (int off = 32; off > 0; off >>= 1) m = min(m, __shfl_xor(m, off, 64));
    if ((threadIdx.x & 63) == 0) atomicMin(minp, m);
}

__global__ void LINK_62689342652831_scatter_kernel(const int* __restrict__ rows,
                                                   const int* __restrict__ cols,
                                                   const float* __restrict__ W,
                                                   const int* __restrict__ minp,
                                                   float* __restrict__ out) {
    int lane = threadIdx.x & 63;
    int gw = (blockIdx.x * blockDim.x + threadIdx.x) >> 6;
    int nw = (gridDim.x * blockDim.x) >> 6;
    int minv = *minp;
    for (int e = gw; e < NUM_EDGES; e += nw) {
        int r = rows[e] - minv;
        int c = cols[e];
        float v = W[(size_t)lane * NUM_NODES + c];
        unsafeAtomicAdd(&out[(size_t)r * 64 + lane], v);
    }
}

__global__ void LINK_62689342652831_logsoftmax_kernel(float* __restrict__ out,
                                                      const float* __restrict__ bias) {
    int lane = threadIdx.x & 63;
    int gw = (blockIdx.x * blockDim.x + threadIdx.x) >> 6;
    int nw = (gridDim.x * blockDim.x) >> 6;
    float b = bias[lane];
    for (int r = gw; r < NUM_NODES; r += nw) {
        float x = out[(size_t)r * 64 + lane] + b;
        float m = x;
        for (int off = 32; off > 0; off >>= 1) m = fmaxf(m, __shfl_xor(m, off, 64));
        float e = expf(x - m);
        float s = e;
        for (int off = 32; off > 0; off >>= 1) s += __shfl_xor(s, off, 64);
        out[(size_t)r * 64 + lane] = x - m - logf(s);
    }
}

extern "C" void kernel_launch(void* const* d_in, const int* in_sizes, int n_in,
                              void* d_out, int out_size, void* d_ws, size_t ws_size,
                              hipStream_t stream) {
    const int* edges = (const int*)d_in[0];
    const int* rows = edges;
    const int* cols = edges + NUM_EDGES;
    const float* W = (const float*)d_in[1];
    const float* bias = (const float*)d_in[2];
    float* out = (float*)d_out;

    // workspace layout
    char* ws = (char*)d_ws;
    const size_t OFF_MIN = 0;
    const size_t OFF_HIST = 256;                       // 400000 B
    const size_t OFF_CHUNK = 512 * 1024;               // 400000 B
    const size_t OFF_BSUM = 960 * 1024;                // 392 B
    const size_t OFF_BOFF = 964 * 1024;                // 392 B
    const size_t OFF_RSTART = 1024 * 1024;             // 400004 B
    const size_t OFF_CURSOR = 1536 * 1024;             // 400000 B
    const size_t OFF_CSR = 2 * 1024 * 1024;            // 12800000 B
    const size_t OFF_WTB = OFF_CSR + (size_t)NUM_EDGES * 4;
    const size_t need = OFF_WTB + (size_t)NUM_NODES * OUT_CH * 2;

    int* minp = (int*)(ws + OFF_MIN);
    int* hist = (int*)(ws + OFF_HIST);
    int* chunk_incl = (int*)(ws + OFF_CHUNK);
    int* block_sums = (int*)(ws + OFF_BSUM);
    int* block_off = (int*)(ws + OFF_BOFF);
    int* row_start = (int*)(ws + OFF_RSTART);
    int* cursor = (int*)(ws + OFF_CURSOR);
    int* csr_col = (int*)(ws + OFF_CSR);
    __hip_bfloat16* Wtb = (__hip_bfloat16*)(ws + OFF_WTB);

    hipMemsetAsync(minp, 0x7f, sizeof(int), stream);

    if (ws_size >= need) {
        hipMemsetAsync(hist, 0, (size_t)NUM_NODES * sizeof(int), stream);
        LINK_62689342652831_minhist_kernel<<<1024, 256, 0, stream>>>(rows, minp, hist);
        LINK_62689342652831_transpose_kernel<<<(NUM_NODES + 63) / 64, 256, 0, stream>>>(W, Wtb);
        LINK_62689342652831_scanA_kernel<<<NSCAN_BLKS, 256, 0, stream>>>(hist, minp,
                                                                         chunk_incl, block_sums);
        LINK_62689342652831_scanB_kernel<<<1, 128, 0, stream>>>(block_sums, block_off);
        LINK_62689342652831_scanC_kernel<<<(NUM_NODES + 255) / 256, 256, 0, stream>>>(
            chunk_incl, hist, minp, block_off, row_start, cursor);
        LINK_62689342652831_csrscatter_kernel<<<2048, 256, 0, stream>>>(rows, cols, minp,
                                                                        cursor, csr_col);
        LINK_62689342652831_spmmcsr_kernel<<<(NUM_NODES * 64 + 255) / 256, 256, 0, stream>>>(
            row_start, csr_col, Wtb, bias, out);
    } else {
        LINK_62689342652831_min_kernel<<<2048, 256, 0, stream>>>(rows, NUM_EDGES, minp);
        hipMemsetAsync(d_out, 0, (size_t)out_size * sizeof(float), stream);
        LINK_62689342652831_scatter_kernel<<<2048, 256, 0, stream>>>(rows, cols, W, minp, out);
        LINK_62689342652831_logsoftmax_kernel<<<4096, 256, 0, stream>>>(out, bias);
    }
}